// Round 15
// baseline (188.000 us; speedup 1.0000x reference)
//
#include <hip/hip_runtime.h>

// MGU forward, swapped-orientation f16 MFMA, 16x16 shape, 8-waves/SIMD.
// B=131072, TAU=20, HID=64. Block = 64 rows, 4 waves; wave owns 16 rows
// (r = lane&15), ALL 64 units. PRE^T = W * S, W in ONE f16 plane
// (R13/R14-validated: absmax 2.44e-4, unchanged from 3-term split).
// sigma keeps B-frag slots lane-local (zero cross-lane, zero LDS writes):
//   sigma(32s + 8q + i) = 16*(2s + (i>>2)) + 4q + (i&3)
//
// R15 rationale (R13+R14 convergence at 101us): VALU-throughput-bound,
// VALU busy ~78us in both; utilization 67-76% is the gap. Fix = 8 waves/SIMD:
//  * __launch_bounds__(256,4) -> VGPR cap 64 (law: cap = 256/arg2, verified
//    R1/R6/R7/R13/R14). Live set trimmed to ~58 by kstep-outer gate order
//    (one B-frag live at a time) -> should fit 64 without spill.
//    SPILL INDICATOR: FETCH_SIZE >> 2.2e4 KB => revert to W=3.
//  * sX LDS tile dropped; x read from global with next-step register
//    prefetch (x tile is L1-resident; 16 addresses/wave-step).
//    LDS = 18.7 KB -> 8 blocks/CU = 148 KB < 160 KB.
//  * grid 2048 = 8 blocks/CU x 256 CU exactly -> one clean round, no tail.
// Aug (bias + x) full split precision via rank-5 aug-MFMA (exp2 domain:
// forget scaled -log2e, candidate +2log2e; quad-rcp activations).
//
// Fragment maps (m89-verified, R5-R14 validated end-to-end):
//   A: lane L holds A[m=L&15][k=(L>>4)*8+i]; B: lane L holds B[k=(L>>4)*8+i][n=L&15]
//   C/D: lane L reg i holds D[m=(L>>4)*4+i][n=L&15]

constexpr int BATCH = 131072;
constexpr int TAU   = 20;
constexpr int HID   = 64;
constexpr int FAN   = 65;
constexpr int NT    = 256;
constexpr int ROWS  = 64;

typedef float    f32x4 __attribute__((ext_vector_type(4)));
typedef _Float16 f16x8 __attribute__((ext_vector_type(8)));
typedef unsigned u32x4 __attribute__((ext_vector_type(4)));

static constexpr float LOG2E  = 1.4426950408889634f;
static constexpr float RCP256 = 0.00390625f;

static __device__ __forceinline__ unsigned pkrtz(float a, float b) {
    return __builtin_bit_cast(unsigned, __builtin_amdgcn_cvt_pkrtz(a, b));
}
#define PK8(a0,a1,a2,a3,a4,a5,a6,a7) \
    __builtin_bit_cast(f16x8, (u32x4){pkrtz(a0,a1), pkrtz(a2,a3), \
                                      pkrtz(a4,a5), pkrtz(a6,a7)})

#define MFMAH(A, B, C) __builtin_amdgcn_mfma_f32_16x16x32_f16((A), (B), (C), 0, 0, 0)

// hi-plane chunk base (halfs) for (g, T, s): 16 chunks x 512
#define HOFF(g, T, s) ((((g) * 8) + ((T) * 2) + (s)) * 512)

#define LD_HI(g, T, s)  (*(const f16x8*)&sWhi[HOFF(g, T, s) + Lx8])
#define LD_AUG(g, T)    (*(const f16x8*)&sAug[augMul * ((g) * 4 + (T)) + augSel])

// F = 1/(1 + exp2(C)); quad rcp (1 v_rcp per 4 elements)
#define SIGF4(F, C) { \
    const float e0_ = __builtin_amdgcn_exp2f(C[0]); \
    const float e1_ = __builtin_amdgcn_exp2f(C[1]); \
    const float e2_ = __builtin_amdgcn_exp2f(C[2]); \
    const float e3_ = __builtin_amdgcn_exp2f(C[3]); \
    const float d0_ = 1.0f + e0_, d1_ = 1.0f + e1_; \
    const float d2_ = 1.0f + e2_, d3_ = 1.0f + e3_; \
    const float d01_ = d0_ * d1_, d23_ = d2_ * d3_; \
    const float ii_  = __builtin_amdgcn_rcpf(d01_ * d23_); \
    const float i01_ = ii_ * d23_, i23_ = ii_ * d01_; \
    F[0] = d1_ * i01_; F[1] = d0_ * i01_; \
    F[2] = d3_ * i23_; F[3] = d2_ * i23_; }

// tanh = 1 - 2/(1 + exp2(C)); S = S + F * (tanh - S); quad rcp
#define UPDF4(S, F, C) { \
    const float e0_ = __builtin_amdgcn_exp2f(C[0]); \
    const float e1_ = __builtin_amdgcn_exp2f(C[1]); \
    const float e2_ = __builtin_amdgcn_exp2f(C[2]); \
    const float e3_ = __builtin_amdgcn_exp2f(C[3]); \
    const float d0_ = 1.0f + e0_, d1_ = 1.0f + e1_; \
    const float d2_ = 1.0f + e2_, d3_ = 1.0f + e3_; \
    const float d01_ = d0_ * d1_, d23_ = d2_ * d3_; \
    const float ii_  = __builtin_amdgcn_rcpf(d01_ * d23_); \
    const float j01_ = -2.0f * (ii_ * d23_), j23_ = -2.0f * (ii_ * d01_); \
    const float t0_ = fmaf(d1_, j01_, 1.0f); \
    const float t1_ = fmaf(d0_, j01_, 1.0f); \
    const float t2_ = fmaf(d3_, j23_, 1.0f); \
    const float t3_ = fmaf(d2_, j23_, 1.0f); \
    S[0] = fmaf(F[0], t0_ - S[0], S[0]); S[1] = fmaf(F[1], t1_ - S[1], S[1]); \
    S[2] = fmaf(F[2], t2_ - S[2], S[2]); S[3] = fmaf(F[3], t3_ - S[3], S[3]); }

__global__ __launch_bounds__(NT, 4) void mgu_fwd(
    const float* __restrict__ x,    // [B, TAU]
    const float* __restrict__ h0,   // [B, HID]
    const float* __restrict__ Wf,   // [HID, FAN]
    const float* __restrict__ bfv,  // [HID]
    const float* __restrict__ Wc,   // [HID, FAN]
    const float* __restrict__ bcv,  // [HID]
    const float* __restrict__ Wo,   // [1, HID]
    const float* __restrict__ bov,  // [1]
    float* __restrict__ out)        // [B, 1]
{
    __shared__ _Float16 sWhi[8192];   // hi planes, 16 chunks x 512 (16 KB)
    __shared__ _Float16 sAug[1032];   // aug chunks (g*4+T)*128+m*8; [1024..1031]=0
    __shared__ float sWo[HID];

    const int tid = threadIdx.x;
    const long rb0 = (long)blockIdx.x * ROWS;

    // ---- one-time: hi planes -> LDS (sigma order, exp2-domain scale)
    for (int idx = tid; idx < 8192; idx += NT) {
        const int i = idx & 7, Li = (idx >> 3) & 63, s = (idx >> 9) & 1,
                  T = (idx >> 10) & 3, g = (idx >> 12) & 1;
        const int u = 16 * (2 * s + (i >> 2)) + 4 * (Li >> 4) + (i & 3); // sigma
        const float* Wg = g ? Wc : Wf;
        const float sc = g ? (2.0f * LOG2E) : (-LOG2E);
        sWhi[HOFF(g, T, s) + (idx & 511)] =
            (_Float16)(sc * Wg[(16 * T + (Li & 15)) * FAN + 1 + u]);
    }
    // ---- one-time: aug chunks (bias + x-column, full split precision)
    if (tid < 128) {
        const int m = tid & 15, T = (tid >> 4) & 3, g = tid >> 6;
        const float* Wg = g ? Wc : Wf;
        const float* bg = g ? bcv : bfv;
        const float sc = g ? (2.0f * LOG2E) : (-LOG2E);
        const float fx = sc * Wg[(16 * T + m) * FAN];
        const float fb = sc * bg[16 * T + m];
        const _Float16 fxh = (_Float16)fx;
        const _Float16 fbh = (_Float16)fb;
        _Float16* c = &sAug[(g * 4 + T) * 128 + m * 8];
        c[0] = fxh;
        c[1] = (_Float16)((fx - (float)fxh) * 256.0f);
        c[2] = fxh;
        c[3] = fbh;
        c[4] = (_Float16)((fb - (float)fbh) * 256.0f);
        c[5] = (_Float16)0.0f; c[6] = (_Float16)0.0f; c[7] = (_Float16)0.0f;
    }
    if (tid < 8) sAug[1024 + tid] = (_Float16)0.0f;
    if (tid < HID) sWo[tid] = Wo[tid];
    __syncthreads();

    const int w = tid >> 6, L = tid & 63, q = L >> 4, r = L & 15;
    const long gr = rb0 + (w * 16 + r);
    const int Lx8 = L * 8;

    const int augMul = (q == 0) ? 128 : 0;
    const int augSel = (q == 0) ? (r * 8) : 1024;   // q>0 -> zero chunk

    const f32x4 z4 = {0.f, 0.f, 0.f, 0.f};

    // ---- state: S_T[i] = H[16T + 4q + i][row]
    f32x4 S0 = *(const f32x4*)&h0[gr * HID +  0 + 4 * q];
    f32x4 S1 = *(const f32x4*)&h0[gr * HID + 16 + 4 * q];
    f32x4 S2 = *(const f32x4*)&h0[gr * HID + 32 + 4 * q];
    f32x4 S3 = *(const f32x4*)&h0[gr * HID + 48 + 4 * q];

    // x read from global (L1-resident tile), register prefetch across steps
    const float* xr = x + gr * TAU;
    float xt = xr[0];

    #pragma unroll 1
    for (int t = 0; t < TAU; ++t) {
        const float xn = (t + 1 < TAU) ? xr[t + 1] : 0.0f;  // prefetch next x

        // ---- aug B-frag: [xh, xh*2^-8, xl, 1, 2^-8, 0,0,0] (q==0 lanes)
        f16x8 augB;
        {
            const _Float16 xh = (_Float16)xt;
            const float xhf = (float)xh;
            unsigned d0 = pkrtz(xhf, xhf * RCP256);
            unsigned d1 = pkrtz(xt - xhf, 1.0f);
            unsigned d2 = pkrtz(RCP256, 0.0f);
            if (q != 0) { d0 = 0; d1 = 0; d2 = 0; }
            augB = __builtin_bit_cast(f16x8, (u32x4){d0, d1, d2, 0u});
        }

        // ---- forget gate: aug, then kstep-outer (one B-frag live at a time)
        f32x4 Cf0 = MFMAH(LD_AUG(0, 0), augB, z4);
        f32x4 Cf1 = MFMAH(LD_AUG(0, 1), augB, z4);
        f32x4 Cf2 = MFMAH(LD_AUG(0, 2), augB, z4);
        f32x4 Cf3 = MFMAH(LD_AUG(0, 3), augB, z4);
        {
            const f16x8 BS0 = PK8(S0[0],S0[1],S0[2],S0[3], S1[0],S1[1],S1[2],S1[3]);
            Cf0 = MFMAH(LD_HI(0, 0, 0), BS0, Cf0);
            Cf1 = MFMAH(LD_HI(0, 1, 0), BS0, Cf1);
            Cf2 = MFMAH(LD_HI(0, 2, 0), BS0, Cf2);
            Cf3 = MFMAH(LD_HI(0, 3, 0), BS0, Cf3);
        }
        {
            const f16x8 BS1 = PK8(S2[0],S2[1],S2[2],S2[3], S3[0],S3[1],S3[2],S3[3]);
            Cf0 = MFMAH(LD_HI(0, 0, 1), BS1, Cf0);
            Cf1 = MFMAH(LD_HI(0, 1, 1), BS1, Cf1);
            Cf2 = MFMAH(LD_HI(0, 2, 1), BS1, Cf2);
            Cf3 = MFMAH(LD_HI(0, 3, 1), BS1, Cf3);
        }

        f32x4 F0, F1, F2, F3;
        SIGF4(F0, Cf0) SIGF4(F1, Cf1) SIGF4(F2, Cf2) SIGF4(F3, Cf3)

        // ---- candidate gate: aug, then kstep-outer with transient BG frags
        f32x4 Cc0 = MFMAH(LD_AUG(1, 0), augB, z4);
        f32x4 Cc1 = MFMAH(LD_AUG(1, 1), augB, z4);
        f32x4 Cc2 = MFMAH(LD_AUG(1, 2), augB, z4);
        f32x4 Cc3 = MFMAH(LD_AUG(1, 3), augB, z4);
        __builtin_amdgcn_s_setprio(1);
        {
            const f16x8 BG0 = PK8(F0[0]*S0[0], F0[1]*S0[1], F0[2]*S0[2], F0[3]*S0[3],
                                  F1[0]*S1[0], F1[1]*S1[1], F1[2]*S1[2], F1[3]*S1[3]);
            Cc0 = MFMAH(LD_HI(1, 0, 0), BG0, Cc0);
            Cc1 = MFMAH(LD_HI(1, 1, 0), BG0, Cc1);
            Cc2 = MFMAH(LD_HI(1, 2, 0), BG0, Cc2);
            Cc3 = MFMAH(LD_HI(1, 3, 0), BG0, Cc3);
        }
        {
            const f16x8 BG1 = PK8(F2[0]*S2[0], F2[1]*S2[1], F2[2]*S2[2], F2[3]*S2[3],
                                  F3[0]*S3[0], F3[1]*S3[1], F3[2]*S3[2], F3[3]*S3[3]);
            Cc0 = MFMAH(LD_HI(1, 0, 1), BG1, Cc0);
            Cc1 = MFMAH(LD_HI(1, 1, 1), BG1, Cc1);
            Cc2 = MFMAH(LD_HI(1, 2, 1), BG1, Cc2);
            Cc3 = MFMAH(LD_HI(1, 3, 1), BG1, Cc3);
        }
        __builtin_amdgcn_s_setprio(0);

        // ---- update: S = S + F * (tanh - S)
        UPDF4(S0, F0, Cc0)
        UPDF4(S1, F1, Cc1)
        UPDF4(S2, F2, Cc2)
        UPDF4(S3, F3, Cc3)

        xt = xn;
    }

    // ---- output: out[row] = bo + Wo . H ; reduce over the 4 q-groups
    const f32x4 wo0 = *(const f32x4*)&sWo[ 0 + 4 * q];
    const f32x4 wo1 = *(const f32x4*)&sWo[16 + 4 * q];
    const f32x4 wo2 = *(const f32x4*)&sWo[32 + 4 * q];
    const f32x4 wo3 = *(const f32x4*)&sWo[48 + 4 * q];
    float acc = 0.0f;
    acc = fmaf(wo0[0], S0[0], acc); acc = fmaf(wo0[1], S0[1], acc);
    acc = fmaf(wo0[2], S0[2], acc); acc = fmaf(wo0[3], S0[3], acc);
    acc = fmaf(wo1[0], S1[0], acc); acc = fmaf(wo1[1], S1[1], acc);
    acc = fmaf(wo1[2], S1[2], acc); acc = fmaf(wo1[3], S1[3], acc);
    acc = fmaf(wo2[0], S2[0], acc); acc = fmaf(wo2[1], S2[1], acc);
    acc = fmaf(wo2[2], S2[2], acc); acc = fmaf(wo2[3], S2[3], acc);
    acc = fmaf(wo3[0], S3[0], acc); acc = fmaf(wo3[1], S3[1], acc);
    acc = fmaf(wo3[2], S3[2], acc); acc = fmaf(wo3[3], S3[3], acc);
    acc += __shfl_xor(acc, 16, 64);
    acc += __shfl_xor(acc, 32, 64);
    if (q == 0) out[gr] = acc + bov[0];
}

extern "C" void kernel_launch(void* const* d_in, const int* in_sizes, int n_in,
                              void* d_out, int out_size, void* d_ws, size_t ws_size,
                              hipStream_t stream) {
    const float* x  = (const float*)d_in[0];
    const float* h0 = (const float*)d_in[1];
    const float* Wf = (const float*)d_in[2];
    const float* bf = (const float*)d_in[3];
    const float* Wc = (const float*)d_in[4];
    const float* bc = (const float*)d_in[5];
    const float* Wo = (const float*)d_in[6];
    const float* bo = (const float*)d_in[7];
    float* out = (float*)d_out;

    hipLaunchKernelGGL(mgu_fwd, dim3(BATCH / ROWS), dim3(NT), 0, stream,
                       x, h0, Wf, bf, Wc, bc, Wo, bo, out);
}

// Round 16
// 101.551 us; speedup vs baseline: 1.8513x; 1.8513x over previous
//
#include <hip/hip_runtime.h>

// MGU forward, swapped-orientation f16 MFMA, hi-plane-only + 6-waves/SIMD.
// B=131072, TAU=20, HID=64. Block = 64 rows, 4 waves; wave owns 16 rows
// (r = lane&15), ALL 64 units. PRE^T = W * S with W in ONE f16 plane.
// Aug (bias + x) full split precision. sigma keeps B-frag slots lane-local
// (zero cross-lane ops, zero LDS writes in the recurrence):
//   sigma(32s + 8q + i) = 16*(2s + (i>>2)) + 4q + (i&3)
//
// === R16: restoration of the R13 optimum (101.5 us) ===
// Session map of decisive experiments:
//  * occupancy: 4->6 waves/SIMD = -31% (R13); 6->8 waves BLOCKED by spill
//    (R15: cap-64 -> FETCH 13x, dur 188us). VGPR law: cap = 256/W
//    {128:4w, 85:6w, 64:8w-spills}. 85/6w is the optimum.
//  * LDS traffic: halved per row via 32x32 MFMA (R14) -> null at 101us.
//  * global/L1 rebalance (R12) -> null. ILP re-schedule (R11) -> null.
//  * VALU trims applied: exp2-domain weights, quad-rcp, pkrtz packing,
//    single-f16-plane weights (absmax unchanged 2.44e-4).
// R13/R14 converge at ~101us, VALU ~76% busy, trans-heavy (32 exp2 + 8 rcp
// per lane-step, algorithmically minimal). This is the practical floor.
// DO NOT perturb register pressure: 84 live vs cap 85 has zero headroom.
//
// Fragment maps (m89-verified, R5-R14 validated end-to-end):
//   A: lane L holds A[m=L&15][k=(L>>4)*8+i]; B: lane L holds B[k=(L>>4)*8+i][n=L&15]
//   C/D: lane L reg i holds D[m=(L>>4)*4+i][n=L&15]

constexpr int BATCH = 131072;
constexpr int TAU   = 20;
constexpr int HID   = 64;
constexpr int FAN   = 65;
constexpr int NT    = 256;
constexpr int ROWS  = 64;

typedef float    f32x4 __attribute__((ext_vector_type(4)));
typedef _Float16 f16x8 __attribute__((ext_vector_type(8)));
typedef unsigned u32x4 __attribute__((ext_vector_type(4)));

static constexpr float LOG2E  = 1.4426950408889634f;
static constexpr float RCP256 = 0.00390625f;

static __device__ __forceinline__ unsigned pkrtz(float a, float b) {
    return __builtin_bit_cast(unsigned, __builtin_amdgcn_cvt_pkrtz(a, b));
}
#define PK8(a0,a1,a2,a3,a4,a5,a6,a7) \
    __builtin_bit_cast(f16x8, (u32x4){pkrtz(a0,a1), pkrtz(a2,a3), \
                                      pkrtz(a4,a5), pkrtz(a6,a7)})

#define MFMAH(A, B, C) __builtin_amdgcn_mfma_f32_16x16x32_f16((A), (B), (C), 0, 0, 0)

// hi-plane chunk base (halfs) for (g, T, s): 16 chunks x 512
#define HOFF(g, T, s) ((((g) * 8) + ((T) * 2) + (s)) * 512)

#define LD_HI(g, T, s)  (*(const f16x8*)&sWhi[HOFF(g, T, s) + Lx8])
#define LD_AUG(g, T)    (*(const f16x8*)&sAug[augMul * ((g) * 4 + (T)) + augSel])

// F = 1/(1 + exp2(C)); quad rcp (1 v_rcp per 4 elements)
#define SIGF4(F, C) { \
    const float e0_ = __builtin_amdgcn_exp2f(C[0]); \
    const float e1_ = __builtin_amdgcn_exp2f(C[1]); \
    const float e2_ = __builtin_amdgcn_exp2f(C[2]); \
    const float e3_ = __builtin_amdgcn_exp2f(C[3]); \
    const float d0_ = 1.0f + e0_, d1_ = 1.0f + e1_; \
    const float d2_ = 1.0f + e2_, d3_ = 1.0f + e3_; \
    const float d01_ = d0_ * d1_, d23_ = d2_ * d3_; \
    const float ii_  = __builtin_amdgcn_rcpf(d01_ * d23_); \
    const float i01_ = ii_ * d23_, i23_ = ii_ * d01_; \
    F[0] = d1_ * i01_; F[1] = d0_ * i01_; \
    F[2] = d3_ * i23_; F[3] = d2_ * i23_; }

// tanh = 1 - 2/(1 + exp2(C)); S = S + F * (tanh - S); quad rcp
#define UPDF4(S, F, C) { \
    const float e0_ = __builtin_amdgcn_exp2f(C[0]); \
    const float e1_ = __builtin_amdgcn_exp2f(C[1]); \
    const float e2_ = __builtin_amdgcn_exp2f(C[2]); \
    const float e3_ = __builtin_amdgcn_exp2f(C[3]); \
    const float d0_ = 1.0f + e0_, d1_ = 1.0f + e1_; \
    const float d2_ = 1.0f + e2_, d3_ = 1.0f + e3_; \
    const float d01_ = d0_ * d1_, d23_ = d2_ * d3_; \
    const float ii_  = __builtin_amdgcn_rcpf(d01_ * d23_); \
    const float j01_ = -2.0f * (ii_ * d23_), j23_ = -2.0f * (ii_ * d01_); \
    const float t0_ = fmaf(d1_, j01_, 1.0f); \
    const float t1_ = fmaf(d0_, j01_, 1.0f); \
    const float t2_ = fmaf(d3_, j23_, 1.0f); \
    const float t3_ = fmaf(d2_, j23_, 1.0f); \
    S[0] = fmaf(F[0], t0_ - S[0], S[0]); S[1] = fmaf(F[1], t1_ - S[1], S[1]); \
    S[2] = fmaf(F[2], t2_ - S[2], S[2]); S[3] = fmaf(F[3], t3_ - S[3], S[3]); }

// one forget-gate tile: aug + 2 hi ksteps + sigmoid (C-reg local)
#define FTILE(T, FT) { \
    f32x4 ch_ = MFMAH(LD_AUG(0, T), augB, z4); \
    ch_ = MFMAH(LD_HI(0, T, 0), BS0, ch_); \
    ch_ = MFMAH(LD_HI(0, T, 1), BS1, ch_); \
    SIGF4(FT, ch_) }

__global__ __launch_bounds__(NT, 3) void mgu_fwd(
    const float* __restrict__ x,    // [B, TAU]
    const float* __restrict__ h0,   // [B, HID]
    const float* __restrict__ Wf,   // [HID, FAN]
    const float* __restrict__ bfv,  // [HID]
    const float* __restrict__ Wc,   // [HID, FAN]
    const float* __restrict__ bcv,  // [HID]
    const float* __restrict__ Wo,   // [1, HID]
    const float* __restrict__ bov,  // [1]
    float* __restrict__ out)        // [B, 1]
{
    __shared__ _Float16 sWhi[8192];   // hi planes, 16 chunks x 512
    __shared__ _Float16 sAug[1032];   // aug chunks (g*4+T)*128+m*8; [1024..1031]=0
    __shared__ float sX[ROWS * TAU];
    __shared__ float sWo[HID];

    const int tid = threadIdx.x;
    const long rb0 = (long)blockIdx.x * ROWS;

    // ---- one-time: hi planes -> LDS (sigma order, exp2-domain scale)
    for (int idx = tid; idx < 8192; idx += NT) {
        const int i = idx & 7, Li = (idx >> 3) & 63, s = (idx >> 9) & 1,
                  T = (idx >> 10) & 3, g = (idx >> 12) & 1;
        const int u = 16 * (2 * s + (i >> 2)) + 4 * (Li >> 4) + (i & 3); // sigma
        const float* Wg = g ? Wc : Wf;
        const float sc = g ? (2.0f * LOG2E) : (-LOG2E);
        sWhi[HOFF(g, T, s) + (idx & 511)] =
            (_Float16)(sc * Wg[(16 * T + (Li & 15)) * FAN + 1 + u]);
    }
    // ---- one-time: aug chunks (bias + x-column, full split precision)
    if (tid < 128) {
        const int m = tid & 15, T = (tid >> 4) & 3, g = tid >> 6;
        const float* Wg = g ? Wc : Wf;
        const float* bg = g ? bcv : bfv;
        const float sc = g ? (2.0f * LOG2E) : (-LOG2E);
        const float fx = sc * Wg[(16 * T + m) * FAN];
        const float fb = sc * bg[16 * T + m];
        const _Float16 fxh = (_Float16)fx;
        const _Float16 fbh = (_Float16)fb;
        _Float16* c = &sAug[(g * 4 + T) * 128 + m * 8];
        c[0] = fxh;
        c[1] = (_Float16)((fx - (float)fxh) * 256.0f);
        c[2] = fxh;
        c[3] = fbh;
        c[4] = (_Float16)((fb - (float)fbh) * 256.0f);
        c[5] = (_Float16)0.0f; c[6] = (_Float16)0.0f; c[7] = (_Float16)0.0f;
    }
    if (tid < 8) sAug[1024 + tid] = (_Float16)0.0f;
    for (int i2 = tid; i2 < ROWS * TAU; i2 += NT) sX[i2] = x[rb0 * TAU + i2];
    if (tid < HID) sWo[tid] = Wo[tid];
    __syncthreads();

    const int w = tid >> 6, L = tid & 63, q = L >> 4, r = L & 15;
    const int lr = w * 16 + r;
    const long gr = rb0 + lr;
    const int Lx8 = L * 8;

    const int augMul = (q == 0) ? 128 : 0;
    const int augSel = (q == 0) ? (r * 8) : 1024;   // q>0 -> zero chunk

    const f32x4 z4 = {0.f, 0.f, 0.f, 0.f};

    // ---- state: S_T[i] = H[16T + 4q + i][r]
    f32x4 S0 = *(const f32x4*)&h0[gr * HID +  0 + 4 * q];
    f32x4 S1 = *(const f32x4*)&h0[gr * HID + 16 + 4 * q];
    f32x4 S2 = *(const f32x4*)&h0[gr * HID + 32 + 4 * q];
    f32x4 S3 = *(const f32x4*)&h0[gr * HID + 48 + 4 * q];

    #pragma unroll 1
    for (int t = 0; t < TAU; ++t) {
        // ---- aug B-frag: [xh, xh*2^-8, xl, 1, 2^-8, 0,0,0] (q==0 lanes)
        const float xt = sX[lr * TAU + t];
        f16x8 augB;
        {
            const _Float16 xh = (_Float16)xt;
            const float xhf = (float)xh;
            unsigned d0 = pkrtz(xhf, xhf * RCP256);
            unsigned d1 = pkrtz(xt - xhf, 1.0f);
            unsigned d2 = pkrtz(RCP256, 0.0f);
            if (q != 0) { d0 = 0; d1 = 0; d2 = 0; }
            augB = __builtin_bit_cast(f16x8, (u32x4){d0, d1, d2, 0u});
        }

        // ---- B-frags of S (single f16 plane, pkrtz)
        const f16x8 BS0 = PK8(S0[0],S0[1],S0[2],S0[3], S1[0],S1[1],S1[2],S1[3]);
        const f16x8 BS1 = PK8(S2[0],S2[1],S2[2],S2[3], S3[0],S3[1],S3[2],S3[3]);

        // ---- candidate-gate aug MFMAs: depend only on x -> issue first
        f32x4 CcH0 = MFMAH(LD_AUG(1, 0), augB, z4);
        f32x4 CcH1 = MFMAH(LD_AUG(1, 1), augB, z4);
        f32x4 CcH2 = MFMAH(LD_AUG(1, 2), augB, z4);
        f32x4 CcH3 = MFMAH(LD_AUG(1, 3), augB, z4);

        // ---- F tiles 0,1 (SIGF overlaps candidate MFMAs)
        f32x4 F0, F1, F2, F3;
        FTILE(0, F0)
        FTILE(1, F1)

        // ---- BG0 (units 0..31) -> candidate kstep 0
        const f32x4 G0 = F0 * S0, G1 = F1 * S1;
        const f16x8 BG0 = PK8(G0[0],G0[1],G0[2],G0[3], G1[0],G1[1],G1[2],G1[3]);
        __builtin_amdgcn_s_setprio(1);
        CcH0 = MFMAH(LD_HI(1, 0, 0), BG0, CcH0);
        CcH1 = MFMAH(LD_HI(1, 1, 0), BG0, CcH1);
        CcH2 = MFMAH(LD_HI(1, 2, 0), BG0, CcH2);
        CcH3 = MFMAH(LD_HI(1, 3, 0), BG0, CcH3);
        __builtin_amdgcn_s_setprio(0);

        // ---- F tiles 2,3 (SIGF overlaps kstep-0 MFMAs)
        FTILE(2, F2)
        FTILE(3, F3)

        // ---- BG1 (units 32..63) -> candidate kstep 1
        const f32x4 G2 = F2 * S2, G3 = F3 * S3;
        const f16x8 BG1 = PK8(G2[0],G2[1],G2[2],G2[3], G3[0],G3[1],G3[2],G3[3]);
        __builtin_amdgcn_s_setprio(1);
        CcH0 = MFMAH(LD_HI(1, 0, 1), BG1, CcH0);
        CcH1 = MFMAH(LD_HI(1, 1, 1), BG1, CcH1);
        CcH2 = MFMAH(LD_HI(1, 2, 1), BG1, CcH2);
        CcH3 = MFMAH(LD_HI(1, 3, 1), BG1, CcH3);
        __builtin_amdgcn_s_setprio(0);

        // ---- update: S = S + F * (tanh - S)
        UPDF4(S0, F0, CcH0)
        UPDF4(S1, F1, CcH1)
        UPDF4(S2, F2, CcH2)
        UPDF4(S3, F3, CcH3)
    }

    // ---- output: out[r] = bo + Wo . H ; reduce over the 4 q-groups
    const f32x4 wo0 = *(const f32x4*)&sWo[ 0 + 4 * q];
    const f32x4 wo1 = *(const f32x4*)&sWo[16 + 4 * q];
    const f32x4 wo2 = *(const f32x4*)&sWo[32 + 4 * q];
    const f32x4 wo3 = *(const f32x4*)&sWo[48 + 4 * q];
    float acc = 0.0f;
    acc = fmaf(wo0[0], S0[0], acc); acc = fmaf(wo0[1], S0[1], acc);
    acc = fmaf(wo0[2], S0[2], acc); acc = fmaf(wo0[3], S0[3], acc);
    acc = fmaf(wo1[0], S1[0], acc); acc = fmaf(wo1[1], S1[1], acc);
    acc = fmaf(wo1[2], S1[2], acc); acc = fmaf(wo1[3], S1[3], acc);
    acc = fmaf(wo2[0], S2[0], acc); acc = fmaf(wo2[1], S2[1], acc);
    acc = fmaf(wo2[2], S2[2], acc); acc = fmaf(wo2[3], S2[3], acc);
    acc = fmaf(wo3[0], S3[0], acc); acc = fmaf(wo3[1], S3[1], acc);
    acc = fmaf(wo3[2], S3[2], acc); acc = fmaf(wo3[3], S3[3], acc);
    acc += __shfl_xor(acc, 16, 64);
    acc += __shfl_xor(acc, 32, 64);
    if (q == 0) out[gr] = acc + bov[0];
}

extern "C" void kernel_launch(void* const* d_in, const int* in_sizes, int n_in,
                              void* d_out, int out_size, void* d_ws, size_t ws_size,
                              hipStream_t stream) {
    const float* x  = (const float*)d_in[0];
    const float* h0 = (const float*)d_in[1];
    const float* Wf = (const float*)d_in[2];
    const float* bf = (const float*)d_in[3];
    const float* Wc = (const float*)d_in[4];
    const float* bc = (const float*)d_in[5];
    const float* Wo = (const float*)d_in[6];
    const float* bo = (const float*)d_in[7];
    float* out = (float*)d_out;

    hipLaunchKernelGGL(mgu_fwd, dim3(BATCH / ROWS), dim3(NT), 0, stream,
                       x, h0, Wf, bf, Wc, bc, Wo, bo, out);
}